// Round 6
// baseline (142.729 us; speedup 1.0000x reference)
//
#include <hip/hip_runtime.h>

typedef short sh8 __attribute__((ext_vector_type(8)));   // 8 bf16
typedef float fx4 __attribute__((ext_vector_type(4)));   // MFMA accumulator
typedef float fl4 __attribute__((ext_vector_type(4)));   // plain float4 (ext vector, nt-store ok)
typedef unsigned short us4 __attribute__((ext_vector_type(4)));

__device__ __forceinline__ unsigned short f2bf(float f) {
    union { float f; unsigned u; } v; v.f = f;
    unsigned r = v.u + 0x7FFFu + ((v.u >> 16) & 1u);   // RNE
    return (unsigned short)(r >> 16);
}
__device__ __forceinline__ unsigned pk2(float a, float b) {
    return (unsigned)f2bf(a) | ((unsigned)f2bf(b) << 16);
}
// async global->LDS, 16B per lane; LDS dest = wave-uniform base + lane*16
__device__ __forceinline__ void gl16(const unsigned short* g, unsigned short* l) {
    __builtin_amdgcn_global_load_lds(
        (const __attribute__((address_space(1))) unsigned int*)g,
        (__attribute__((address_space(3))) unsigned int*)l, 16, 0, 0);
}

// ---------------- prep: cvt inputs + transpose weights + pack mask (one kernel) -----------
__global__ __launch_bounds__(256) void prep(const float* __restrict__ x0,
                                            const float* __restrict__ x1,
                                            const float* __restrict__ x2,
                                            const float* __restrict__ w0,
                                            const float* __restrict__ w1,
                                            const float* __restrict__ w2,
                                            const float* __restrict__ w3,
                                            const int* __restrict__ mask,
                                            unsigned short* __restrict__ in_bf,
                                            unsigned short* __restrict__ wt,
                                            unsigned long long* __restrict__ mp2) {
    __shared__ float tw[32][33];
    const int bid = blockIdx.x, tid = threadIdx.x;
    if (bid < 1536) {                               // cvt: 3 inputs x 512 blocks
        const int z = bid >> 9, xb = bid & 511;
        const float* src = z == 0 ? x0 : (z == 1 ? x1 : x2);
        unsigned short* dst = in_bf + (size_t)z * 2097152;
        for (int i = xb * 256 + tid; i < 524288; i += 131072) {
            float4 v = ((const float4*)src)[i];
            ushort4 o;
            o.x = f2bf(v.x); o.y = f2bf(v.y); o.z = f2bf(v.z); o.w = f2bf(v.w);
            ((ushort4*)dst)[i] = o;
        }
    } else if (bid < 2560) {                        // transpose_w: 4 x (16x16) blocks
        const int t = bid - 1536;
        const int z = t >> 8, bx = t & 15, by = (t >> 4) & 15;
        const float* W = z == 0 ? w0 : z == 1 ? w1 : z == 2 ? w2 : w3;
        unsigned short* Wt = wt + (size_t)z * 262144;
        const int tx = tid & 31, ty = tid >> 5;
        #pragma unroll
        for (int i = 0; i < 4; ++i)
            tw[ty + i * 8][tx] = W[(size_t)(by * 32 + ty + i * 8) * 512 + bx * 32 + tx];
        __syncthreads();
        #pragma unroll
        for (int i = 0; i < 4; ++i)
            Wt[(size_t)(bx * 32 + ty + i * 8) * 512 + by * 32 + tx] = f2bf(tw[tx][ty + i * 8]);
    } else {                                        // pack_mask: 16 blocks (2 b x 8)
        const int p = bid - 2560;
        const int b = p >> 3, k = (p & 7) * 256 + tid;
        int v = mask[(size_t)b * 4194304 + k];
        unsigned long long bal = __ballot(v != 0);
        if ((tid & 63) == 0) mp2[b * 32 + (k >> 6)] = bal;
    }
}

// ---------------- GEMM: C[4096,512] = A_bf16 @ Wt^T + bias ----------------
// MODE 0: z in {K,V,Q}. z==0/2 -> qkv layout [z][B][H][L][64] (q scaled); z==1 -> VtB [bh][64][2048].
// MODE 1: out fp32 row-major [4096][512].
template <int MODE>
__global__ __launch_bounds__(256) void gemm_k(const unsigned short* __restrict__ Aall,
                                              const unsigned short* __restrict__ Wtall,
                                              const float* __restrict__ b0,
                                              const float* __restrict__ b1,
                                              const float* __restrict__ b2,
                                              void* __restrict__ outp,
                                              unsigned short* __restrict__ VtB) {
    const int z = blockIdx.z;
    const unsigned short* A  = Aall  + (size_t)z * (4096 * 512);
    const unsigned short* Bt = Wtall + (size_t)z * (512 * 512);
    const float* bias = (MODE == 0) ? (z == 0 ? b0 : (z == 1 ? b1 : b2)) : b0;

    __shared__ __align__(16) unsigned short As[128 * 64];   // XOR-swizzled chunks
    __shared__ __align__(16) unsigned short Bs[64 * 64];

    const int tid = threadIdx.x;
    const int wid = tid >> 6, lane = tid & 63, lr = lane & 15, lg = lane >> 4;
    const int wr = wid >> 1, wc = wid & 1;
    const int mblk = blockIdx.x * 128, nblk = blockIdx.y * 64;
    const int r7 = lr & 7;

    fx4 acc[4][2];
    #pragma unroll
    for (int mf = 0; mf < 4; ++mf)
        #pragma unroll
        for (int nf = 0; nf < 2; ++nf)
            #pragma unroll
            for (int j = 0; j < 4; ++j) acc[mf][nf][j] = 0.f;

    for (int kt = 0; kt < 8; ++kt) {
        __syncthreads();                         // WAR
        #pragma unroll
        for (int g = 0; g < 4; ++g) {            // A: 1024 chunks, 256/wave
            int ci = wid * 256 + g * 64 + lane;
            int r = ci >> 3, c = (ci & 7) ^ (r & 7);
            gl16(A + (size_t)(mblk + r) * 512 + kt * 64 + c * 8, &As[(wid * 256 + g * 64) * 8]);
        }
        #pragma unroll
        for (int g = 0; g < 2; ++g) {            // B: 512 chunks, 128/wave
            int ci = wid * 128 + g * 64 + lane;
            int r = ci >> 3, c = (ci & 7) ^ (r & 7);
            gl16(Bt + (size_t)(nblk + r) * 512 + kt * 64 + c * 8, &Bs[(wid * 128 + g * 64) * 8]);
        }
        __syncthreads();                         // RAW (compiler drains vmcnt)
        #pragma unroll
        for (int d = 0; d < 2; ++d) {
            sh8 af[4], bf[2];
            #pragma unroll
            for (int mf = 0; mf < 4; ++mf)
                af[mf] = *(const sh8*)&As[(wr * 64 + mf * 16 + lr) * 64 + (((d * 4 + lg) ^ r7) * 8)];
            #pragma unroll
            for (int nf = 0; nf < 2; ++nf)
                bf[nf] = *(const sh8*)&Bs[(wc * 32 + nf * 16 + lr) * 64 + (((d * 4 + lg) ^ r7) * 8)];
            #pragma unroll
            for (int mf = 0; mf < 4; ++mf)
                #pragma unroll
                for (int nf = 0; nf < 2; ++nf)
                    acc[mf][nf] = __builtin_amdgcn_mfma_f32_16x16x32_bf16(af[mf], bf[nf], acc[mf][nf], 0, 0, 0);
        }
    }

    if (MODE == 0 && z == 1) {
        // V: write transposed only -> VtB[(b*8+h)*64 + dd][lq]
        #pragma unroll
        for (int nf = 0; nf < 2; ++nf) {
            int n = nblk + wc * 32 + nf * 16 + lr;
            float bv = bias[n];
            int h = n >> 6, dd = n & 63;
            #pragma unroll
            for (int mf = 0; mf < 4; ++mf) {
                int m0 = mblk + wr * 64 + mf * 16 + lg * 4;
                int bb = m0 >> 11, lq = m0 & 2047;
                ushort4 o;
                o.x = f2bf(acc[mf][nf][0] + bv);
                o.y = f2bf(acc[mf][nf][1] + bv);
                o.z = f2bf(acc[mf][nf][2] + bv);
                o.w = f2bf(acc[mf][nf][3] + bv);
                *(ushort4*)(VtB + ((size_t)(bb * 8 + h) * 64 + dd) * 2048 + lq) = o;
            }
        }
    } else {
        #pragma unroll
        for (int nf = 0; nf < 2; ++nf) {
            int n = nblk + wc * 32 + nf * 16 + lr;
            float bv = bias[n];
            #pragma unroll
            for (int mf = 0; mf < 4; ++mf) {
                #pragma unroll
                for (int j = 0; j < 4; ++j) {
                    int m = mblk + wr * 64 + mf * 16 + lg * 4 + j;
                    float val = acc[mf][nf][j] + bv;
                    if (MODE == 0) {
                        if (z == 2) val *= 0.125f;      // 1/sqrt(64) folded into q
                        int bb = m >> 11, lq = m & 2047, h = n >> 6, dd = n & 63;
                        ((unsigned short*)outp)[(size_t)(((z * 2 + bb) * 8 + h) * 2048 + lq) * 64 + dd] = f2bf(val);
                    } else {
                        ((float*)outp)[(size_t)m * 512 + n] = val;
                    }
                }
            }
        }
    }
}

// ---------------- fused attention: wave-level k-split, direct-L2 fragments ----------------
// Block = (qb, bh): 64 q x 2048 k. Wave w owns k-range [w*512, w*512+512) = 8 tiles of 64,
// covering ALL 64 q (4 q-fragments). No staging, no hot-loop barriers.
__global__ __launch_bounds__(256, 2) void attn_fused(const unsigned short* __restrict__ qkv,
                                                     const unsigned short* __restrict__ Vt,
                                                     const unsigned long long* __restrict__ mp2,
                                                     float* __restrict__ aw,
                                                     unsigned short* __restrict__ cv) {
    const int bid = blockIdx.x;
    const int swz = (bid & 7) * 64 + (bid >> 3);           // XCD-chunked (512 % 8 == 0)
    const int qb = swz & 31, bh = swz >> 5;
    const int b = bh >> 3, h = bh & 7;
    const unsigned short* Kg = qkv + (size_t)bh * 131072;
    const unsigned short* Vg = Vt + (size_t)bh * 131072;    // [64 d][2048 k]
    const unsigned short* Qg = qkv + 2 * 2097152 + (size_t)bh * 131072 + (size_t)qb * 4096;

    __shared__ __align__(16) unsigned short Pb[4][4096];    // per-wave P tile [64q][64k], swizzled
    __shared__ float2 sm[4][64];                            // per-wave (m,l) per q
    __shared__ __align__(16) float pvr[64][68];             // PV merge buffer

    const int tid = threadIdx.x, w = tid >> 6, lane = tid & 63, lr = lane & 15, lg = lane >> 4;
    const int r7 = lr & 7;

    // Q fragments for all 4 q-groups (B-operand)
    sh8 qf[4][2];
    #pragma unroll
    for (int qg = 0; qg < 4; ++qg) {
        qf[qg][0] = *(const sh8*)(Qg + (qg * 16 + lr) * 64 + lg * 8);
        qf[qg][1] = *(const sh8*)(Qg + (qg * 16 + lr) * 64 + 32 + lg * 8);
    }

    // ---------- phase A: per-wave (m,l) over its 8 k-tiles ----------
    float m_[4], l_[4];
    #pragma unroll
    for (int qg = 0; qg < 4; ++qg) { m_[qg] = -3e38f; l_[qg] = 0.f; }

    for (int t = 0; t < 8; ++t) {
        unsigned long long mw = mp2[b * 32 + w * 8 + t];
        if (mw == 0ull) continue;
        const unsigned short* Kt = Kg + (size_t)(w * 8 + t) * 4096;
        sh8 kf0[4], kf1[4];
        #pragma unroll
        for (int mt = 0; mt < 4; ++mt) {
            kf0[mt] = *(const sh8*)(Kt + (mt * 16 + lr) * 64 + lg * 8);
            kf1[mt] = *(const sh8*)(Kt + (mt * 16 + lr) * 64 + 32 + lg * 8);
        }
        bool full = (mw == ~0ull);
        #pragma unroll
        for (int qg = 0; qg < 4; ++qg) {
            fx4 a[4];
            #pragma unroll
            for (int mt = 0; mt < 4; ++mt) {
                fx4 zz; zz[0] = 0.f; zz[1] = 0.f; zz[2] = 0.f; zz[3] = 0.f;
                zz = __builtin_amdgcn_mfma_f32_16x16x32_bf16(kf0[mt], qf[qg][0], zz, 0, 0, 0);
                a[mt] = __builtin_amdgcn_mfma_f32_16x16x32_bf16(kf1[mt], qf[qg][1], zz, 0, 0, 0);
            }
            float sv[16], tmax = -3e38f;
            #pragma unroll
            for (int mt = 0; mt < 4; ++mt)
                #pragma unroll
                for (int j = 0; j < 4; ++j) {
                    int kl = mt * 16 + lg * 4 + j;
                    bool ok = full || ((mw >> kl) & 1ull);
                    float s = ok ? a[mt][j] : -3e38f;
                    sv[mt * 4 + j] = s; tmax = fmaxf(tmax, s);
                }
            float mnew = fmaxf(m_[qg], tmax);
            if (mnew > -1e37f) {
                float ps = 0.f;
                #pragma unroll
                for (int i = 0; i < 16; ++i) ps += __expf(sv[i] - mnew);
                l_[qg] = l_[qg] * __expf(m_[qg] - mnew) + ps;
                m_[qg] = mnew;
            }
        }
    }
    // in-wave merge across lg groups
    #pragma unroll
    for (int qg = 0; qg < 4; ++qg) {
        #pragma unroll
        for (int off = 16; off <= 32; off <<= 1) {
            float mo = __shfl_xor(m_[qg], off), lo = __shfl_xor(l_[qg], off);
            float mn = fmaxf(m_[qg], mo);
            l_[qg] = l_[qg] * __expf(m_[qg] - mn) + lo * __expf(mo - mn);
            m_[qg] = mn;
        }
        if (lg == 0) sm[w][qg * 16 + lr] = make_float2(m_[qg], l_[qg]);
    }
    __syncthreads();
    // cross-wave merge -> (M, rinv) per q-row
    float M[4], R[4];
    #pragma unroll
    for (int qg = 0; qg < 4; ++qg) {
        float mm = -3e38f;
        float2 pv4[4];
        #pragma unroll
        for (int u = 0; u < 4; ++u) { pv4[u] = sm[u][qg * 16 + lr]; mm = fmaxf(mm, pv4[u].x); }
        float ll = 0.f;
        #pragma unroll
        for (int u = 0; u < 4; ++u) ll += pv4[u].y * __expf(pv4[u].x - mm);
        M[qg] = (ll > 0.f) ? mm : 0.f;
        R[qg] = (ll > 0.f) ? 1.f / ll : 0.f;
    }

    // ---------- phase B: recompute S^T, write normalized aw (nt), accumulate PV partial ----
    fx4 acco[4][4];
    #pragma unroll
    for (int md = 0; md < 4; ++md)
        #pragma unroll
        for (int qg = 0; qg < 4; ++qg) { acco[md][qg][0]=0.f; acco[md][qg][1]=0.f; acco[md][qg][2]=0.f; acco[md][qg][3]=0.f; }

    float* awb = aw + (size_t)bh * 4194304 + (size_t)(qb * 64) * 2048;
    unsigned short* PbW = Pb[w];

    for (int t = 0; t < 8; ++t) {
        const int ktg = w * 8 + t;
        unsigned long long mw = mp2[b * 32 + ktg];
        if (mw == 0ull) {                          // zero-fill aw for this tile, skip compute
            fl4 z4 = {0.f, 0.f, 0.f, 0.f};
            #pragma unroll
            for (int qg = 0; qg < 4; ++qg)
                #pragma unroll
                for (int mt = 0; mt < 4; ++mt)
                    __builtin_nontemporal_store(z4,
                        (fl4*)(awb + (size_t)(qg * 16 + lr) * 2048 + ktg * 64 + mt * 16 + lg * 4));
            continue;
        }
        const unsigned short* Kt = Kg + (size_t)ktg * 4096;
        sh8 kf0[4], kf1[4];
        #pragma unroll
        for (int mt = 0; mt < 4; ++mt) {
            kf0[mt] = *(const sh8*)(Kt + (mt * 16 + lr) * 64 + lg * 8);
            kf1[mt] = *(const sh8*)(Kt + (mt * 16 + lr) * 64 + 32 + lg * 8);
        }
        bool full = (mw == ~0ull);
        #pragma unroll
        for (int qg = 0; qg < 4; ++qg) {
            fx4 a[4];
            #pragma unroll
            for (int mt = 0; mt < 4; ++mt) {
                fx4 zz; zz[0] = 0.f; zz[1] = 0.f; zz[2] = 0.f; zz[3] = 0.f;
                zz = __builtin_amdgcn_mfma_f32_16x16x32_bf16(kf0[mt], qf[qg][0], zz, 0, 0, 0);
                a[mt] = __builtin_amdgcn_mfma_f32_16x16x32_bf16(kf1[mt], qf[qg][1], zz, 0, 0, 0);
            }
            #pragma unroll
            for (int mt = 0; mt < 4; ++mt) {
                fl4 pw;
                #pragma unroll
                for (int j = 0; j < 4; ++j) {
                    int kl = mt * 16 + lg * 4 + j;
                    bool ok = full || ((mw >> kl) & 1ull);
                    float p = ok ? __expf(a[mt][j] - M[qg]) * R[qg] : 0.f;
                    pw[j] = p;
                }
                __builtin_nontemporal_store(pw,
                    (fl4*)(awb + (size_t)(qg * 16 + lr) * 2048 + ktg * 64 + mt * 16 + lg * 4));
                int sc = (mt * 2 + (lg >> 1)) ^ r7;
                *(uint2*)&PbW[(qg * 16 + lr) * 64 + sc * 8 + (lg & 1) * 4] =
                    make_uint2(pk2(pw[0], pw[1]), pk2(pw[2], pw[3]));
            }
        }
        asm volatile("s_waitcnt lgkmcnt(0)" ::: "memory");   // wave-private Pb RAW
        __builtin_amdgcn_sched_barrier(0);
        sh8 pf[4][2];
        #pragma unroll
        for (int qg = 0; qg < 4; ++qg) {
            pf[qg][0] = *(const sh8*)&PbW[(qg * 16 + lr) * 64 + ((lg ^ r7) * 8)];
            pf[qg][1] = *(const sh8*)&PbW[(qg * 16 + lr) * 64 + (((4 + lg) ^ r7) * 8)];
        }
        __builtin_amdgcn_s_setprio(1);
        #pragma unroll
        for (int md = 0; md < 4; ++md) {
            sh8 vf0 = *(const sh8*)(Vg + (size_t)(md * 16 + lr) * 2048 + ktg * 64 + lg * 8);
            sh8 vf1 = *(const sh8*)(Vg + (size_t)(md * 16 + lr) * 2048 + ktg * 64 + 32 + lg * 8);
            #pragma unroll
            for (int qg = 0; qg < 4; ++qg) {
                acco[md][qg] = __builtin_amdgcn_mfma_f32_16x16x32_bf16(vf0, pf[qg][0], acco[md][qg], 0, 0, 0);
                acco[md][qg] = __builtin_amdgcn_mfma_f32_16x16x32_bf16(vf1, pf[qg][1], acco[md][qg], 0, 0, 0);
            }
        }
        __builtin_amdgcn_s_setprio(0);
    }

    // ---------- PV merge across waves (sequential passes into pvr) ----------
    #pragma unroll
    for (int pass = 0; pass < 4; ++pass) {
        if (w == pass) {
            #pragma unroll
            for (int md = 0; md < 4; ++md)
                #pragma unroll
                for (int qg = 0; qg < 4; ++qg) {
                    float* p = &pvr[qg * 16 + lr][md * 16 + lg * 4];
                    if (pass == 0) {
                        *(fx4*)p = acco[md][qg];
                    } else {
                        fx4 c = *(fx4*)p;
                        c[0] += acco[md][qg][0]; c[1] += acco[md][qg][1];
                        c[2] += acco[md][qg][2]; c[3] += acco[md][qg][3];
                        *(fx4*)p = c;
                    }
                }
        }
        __syncthreads();
    }
    // cv write: wave w takes d-block md=w
    #pragma unroll
    for (int qg = 0; qg < 4; ++qg) {
        fx4 c = *(fx4*)&pvr[qg * 16 + lr][w * 16 + lg * 4];
        us4 o;
        o[0] = f2bf(c[0]); o[1] = f2bf(c[1]); o[2] = f2bf(c[2]); o[3] = f2bf(c[3]);
        __builtin_nontemporal_store(o,
            (us4*)(cv + (size_t)(b * 2048 + qb * 64 + qg * 16 + lr) * 512 + h * 64 + w * 16 + lg * 4));
    }
}

// ---------------- launch ----------------
extern "C" void kernel_launch(void* const* d_in, const int* in_sizes, int n_in,
                              void* d_out, int out_size, void* d_ws, size_t ws_size,
                              hipStream_t stream) {
    const float* key_in   = (const float*)d_in[0];
    const float* value_in = (const float*)d_in[1];
    const float* query_in = (const float*)d_in[2];
    const float* Wk = (const float*)d_in[3];
    const float* bk = (const float*)d_in[4];
    const float* Wv = (const float*)d_in[5];
    const float* bv = (const float*)d_in[6];
    const float* Wq = (const float*)d_in[7];
    const float* bq = (const float*)d_in[8];
    const float* Wo = (const float*)d_in[9];
    const float* bo = (const float*)d_in[10];
    const int* mask = (const int*)d_in[11];

    char* ws = (char*)d_ws;
    unsigned short* in_bf = (unsigned short*)(ws);                  // 12.58M
    unsigned short* qkv   = (unsigned short*)(ws + 12582912);       // 12.58M: K slot0, Q slot2
    unsigned short* cvb   = (unsigned short*)(ws + 12582912 + 4194304); // overlays unused V slot1
    unsigned short* wt    = (unsigned short*)(ws + 25165824);       // 2.10M
    unsigned short* VtB   = (unsigned short*)(ws + 27262976);       // 4.19M
    unsigned long long* mp2 = (unsigned long long*)(ws + 31457280); // 512 B

    float* out_cv = (float*)d_out;
    float* out_aw = (float*)d_out + 2097152;

    prep<<<dim3(2576), 256, 0, stream>>>(key_in, value_in, query_in,
                                         Wk, Wv, Wq, Wo, mask, in_bf, wt, mp2);
    gemm_k<0><<<dim3(32, 8, 3), 256, 0, stream>>>(in_bf, wt, bk, bv, bq, qkv, VtB);
    attn_fused<<<dim3(512), 256, 0, stream>>>(qkv, VtB, mp2, out_aw, cvb);
    gemm_k<1><<<dim3(32, 8, 1), 256, 0, stream>>>(cvb, wt + 3 * 262144, bo, bo, bo, out_cv, (unsigned short*)nullptr);
}